// Round 1
// baseline (919.734 us; speedup 1.0000x reference)
//
#include <hip/hip_runtime.h>
#include <hip/hip_bf16.h>

// Problem constants (match reference)
constexpr int cN = 50000;
constexpr int cE = 800000;
constexpr int cNUM_CLASSES = 40;
constexpr int cFEAT_DIM = 256;
constexpr int cFEAT_HID = 64;
constexpr int cDEG_HID = 32;
constexpr int cHID = 128;
constexpr int cIN_CH = cNUM_CLASSES + cFEAT_HID + cDEG_HID; // 136
constexpr int cMAX_DEG = 256;

// ---------------- degree histograms ----------------
__global__ void degree_kernel(const int* __restrict__ edge,
                              int* __restrict__ count_src, int* __restrict__ count_dst) {
    int e = blockIdx.x * blockDim.x + threadIdx.x;
    if (e < cE) {
        atomicAdd(&count_src[edge[e]], 1);
        atomicAdd(&count_dst[edge[cE + e]], 1);
    }
}

// ---------------- exclusive scan of count_dst -> rowptr (single block) ----------------
__global__ void scan_kernel(const int* __restrict__ cnt, int* __restrict__ rowptr,
                            int* __restrict__ cursor) {
    __shared__ int lds[1024];
    int tid = threadIdx.x;
    constexpr int CHUNK = (cN + 1023) / 1024; // 49
    int begin = tid * CHUNK;
    int end = begin + CHUNK;
    if (end > cN) end = cN;
    int s = 0;
    for (int i = begin; i < end; ++i) s += cnt[i];
    lds[tid] = s;
    __syncthreads();
    // inclusive Hillis-Steele scan over 1024
    for (int off = 1; off < 1024; off <<= 1) {
        int v = (tid >= off) ? lds[tid - off] : 0;
        __syncthreads();
        lds[tid] += v;
        __syncthreads();
    }
    int run = (tid == 0) ? 0 : lds[tid - 1];
    for (int i = begin; i < end; ++i) {
        rowptr[i] = run;
        cursor[i] = run;
        run += cnt[i];
    }
    if (tid == 1023) rowptr[cN] = lds[1023];
}

// ---------------- scatter edges into CSR (by dst) ----------------
__global__ void scatter_kernel(const int* __restrict__ edge, int* __restrict__ cursor,
                               int* __restrict__ adj) {
    int e = blockIdx.x * blockDim.x + threadIdx.x;
    if (e < cE) {
        int d = edge[cE + e];
        int pos = atomicAdd(&cursor[d], 1);
        adj[pos] = edge[e];
    }
}

// ---------------- dinv = rsqrt(count_dst + 1) ----------------
__global__ void dinv_kernel(const int* __restrict__ count_dst, float* __restrict__ dinv) {
    int i = blockIdx.x * blockDim.x + threadIdx.x;
    if (i < cN) {
        dinv[i] = rsqrtf((float)(count_dst[i] + 1));
    }
}

// ---------------- x[:, 0:40] = logits ----------------
__global__ void copy_logits_kernel(const float* __restrict__ logits, float* __restrict__ x) {
    int idx = blockIdx.x * blockDim.x + threadIdx.x;
    if (idx < cN * cNUM_CLASSES) {
        int i = idx / cNUM_CLASSES;
        int c = idx - i * cNUM_CLASSES;
        x[(size_t)i * cIN_CH + c] = logits[idx];
    }
}

// ---------------- x[:, 104:136] = deg_table[clip(deg)] ----------------
__global__ void degemb_kernel(const int* __restrict__ count_src, const int* __restrict__ count_dst,
                              const float* __restrict__ deg_table, float* __restrict__ x) {
    int idx = blockIdx.x * blockDim.x + threadIdx.x;
    if (idx < cN * cDEG_HID) {
        int i = idx / cDEG_HID;
        int j = idx - i * cDEG_HID;
        int deg = count_src[i] + count_dst[i];
        if (deg > cMAX_DEG - 1) deg = cMAX_DEG - 1;
        x[(size_t)i * cIN_CH + cNUM_CLASSES + cFEAT_HID + j] = deg_table[deg * cDEG_HID + j];
    }
}

// ---------------- x[:, 40:104] = features @ Wf + bf ----------------
__global__ void featlin_kernel(const float* __restrict__ features, const float* __restrict__ Wf,
                               const float* __restrict__ bf, float* __restrict__ x) {
    __shared__ float row[cFEAT_DIM];
    int i = blockIdx.x;
    int tid = threadIdx.x; // 64 threads
    for (int k = tid; k < cFEAT_DIM; k += 64) row[k] = features[(size_t)i * cFEAT_DIM + k];
    __syncthreads();
    float acc = bf[tid];
    #pragma unroll 8
    for (int k = 0; k < cFEAT_DIM; ++k) acc += row[k] * Wf[k * cFEAT_HID + tid];
    x[(size_t)i * cIN_CH + cNUM_CLASSES + tid] = acc;
}

// ---------------- out[i,:] = in[i,:] @ W  (one row per block) ----------------
template <int K, int OUTC, int BLOCK>
__global__ void rowgemm_kernel(const float* __restrict__ in, const float* __restrict__ W,
                               float* __restrict__ out) {
    __shared__ float row[K];
    int i = blockIdx.x;
    int tid = threadIdx.x;
    for (int k = tid; k < K; k += BLOCK) row[k] = in[(size_t)i * K + k];
    __syncthreads();
    if (tid < OUTC) {
        float acc = 0.f;
        #pragma unroll 8
        for (int k = 0; k < K; ++k) acc += row[k] * W[k * OUTC + tid];
        out[(size_t)i * OUTC + tid] = acc;
    }
}

// ---------------- GCN aggregate: out[i,c] = di*sum_j dinv[j]*t[j,c] + di*di*t[i,c] + b[c] ----------------
template <int OUTC, bool RELU>
__global__ void agg_kernel(const float* __restrict__ t, const int* __restrict__ rowptr,
                           const int* __restrict__ adj, const float* __restrict__ dinv,
                           const float* __restrict__ b, float* __restrict__ out) {
    int i = blockIdx.x;
    int tid = threadIdx.x;
    float di = dinv[i];
    int beg = rowptr[i], end = rowptr[i + 1];
    if (tid < OUTC) {
        float acc = 0.f;
        for (int e = beg; e < end; ++e) {
            int j = adj[e];
            acc += dinv[j] * t[(size_t)j * OUTC + tid];
        }
        float r = di * acc + di * di * t[(size_t)i * OUTC + tid] + b[tid];
        if (RELU) r = fmaxf(r, 0.f);
        out[(size_t)i * OUTC + tid] = r;
    }
}

extern "C" void kernel_launch(void* const* d_in, const int* in_sizes, int n_in,
                              void* d_out, int out_size, void* d_ws, size_t ws_size,
                              hipStream_t stream) {
    const float* logits    = (const float*)d_in[0];
    const float* features  = (const float*)d_in[1];
    const int*   edge      = (const int*)d_in[2];
    const float* Wf        = (const float*)d_in[3];
    const float* bf        = (const float*)d_in[4];
    const float* deg_table = (const float*)d_in[5];
    const float* W1        = (const float*)d_in[6];
    const float* b1        = (const float*)d_in[7];
    const float* W2        = (const float*)d_in[8];
    const float* b2        = (const float*)d_in[9];
    const float* W3        = (const float*)d_in[10];
    const float* b3        = (const float*)d_in[11];
    float* out = (float*)d_out;

    // workspace carve-up
    int* count_src = (int*)d_ws;                 // N
    int* count_dst = count_src + cN;             // N
    int* rowptr    = count_dst + cN;             // N+1
    int* cursor    = rowptr + cN + 16;           // N (padded start)
    int* adj       = cursor + cN;                // E
    float* dinv    = (float*)(adj + cE);         // N
    float* x       = dinv + cN;                  // N*IN_CH
    float* t       = x + (size_t)cN * cIN_CH;    // N*HID
    float* h       = t + (size_t)cN * cHID;      // N*HID

    // zero the two histogram arrays (ws is poisoned 0xAA before every call)
    hipMemsetAsync(count_src, 0, 2 * cN * sizeof(int), stream);

    degree_kernel<<<(cE + 255) / 256, 256, 0, stream>>>(edge, count_src, count_dst);
    scan_kernel<<<1, 1024, 0, stream>>>(count_dst, rowptr, cursor);
    scatter_kernel<<<(cE + 255) / 256, 256, 0, stream>>>(edge, cursor, adj);
    dinv_kernel<<<(cN + 255) / 256, 256, 0, stream>>>(count_dst, dinv);

    copy_logits_kernel<<<(cN * cNUM_CLASSES + 255) / 256, 256, 0, stream>>>(logits, x);
    degemb_kernel<<<(cN * cDEG_HID + 255) / 256, 256, 0, stream>>>(count_src, count_dst, deg_table, x);
    featlin_kernel<<<cN, 64, 0, stream>>>(features, Wf, bf, x);

    // conv1: t = x @ W1 ; h = relu(agg(t) + b1)
    rowgemm_kernel<cIN_CH, cHID, 128><<<cN, 128, 0, stream>>>(x, W1, t);
    agg_kernel<cHID, true><<<cN, 128, 0, stream>>>(t, rowptr, adj, dinv, b1, h);

    // conv2: t = h @ W2 ; h = relu(agg(t) + b2)
    rowgemm_kernel<cHID, cHID, 128><<<cN, 128, 0, stream>>>(h, W2, t);
    agg_kernel<cHID, true><<<cN, 128, 0, stream>>>(t, rowptr, adj, dinv, b2, h);

    // conv3: t = h @ W3 ; out = agg(t) + b3
    rowgemm_kernel<cHID, cNUM_CLASSES, 64><<<cN, 64, 0, stream>>>(h, W3, t);
    agg_kernel<cNUM_CLASSES, false><<<cN, 64, 0, stream>>>(t, rowptr, adj, dinv, b3, out);
}

// Round 2
// 659.255 us; speedup vs baseline: 1.3951x; 1.3951x over previous
//
#include <hip/hip_runtime.h>
#include <hip/hip_bf16.h>

// Problem constants (match reference)
constexpr int cN = 50000;
constexpr int cE = 800000;
constexpr int cNUM_CLASSES = 40;
constexpr int cFEAT_DIM = 256;
constexpr int cFEAT_HID = 64;
constexpr int cDEG_HID = 32;
constexpr int cHID = 128;
constexpr int cIN_CH = cNUM_CLASSES + cFEAT_HID + cDEG_HID; // 136
constexpr int cMAX_DEG = 256;

// ---------------- degree histograms ----------------
__global__ void degree_kernel(const int* __restrict__ edge,
                              int* __restrict__ count_src, int* __restrict__ count_dst) {
    int e = blockIdx.x * blockDim.x + threadIdx.x;
    if (e < cE) {
        atomicAdd(&count_src[edge[e]], 1);
        atomicAdd(&count_dst[edge[cE + e]], 1);
    }
}

// ---------------- exclusive scan of count_dst -> rowptr (single block) ----------------
__global__ void scan_kernel(const int* __restrict__ cnt, int* __restrict__ rowptr,
                            int* __restrict__ cursor) {
    __shared__ int lds[1024];
    int tid = threadIdx.x;
    constexpr int CHUNK = (cN + 1023) / 1024; // 49
    int begin = tid * CHUNK;
    int end = begin + CHUNK;
    if (end > cN) end = cN;
    int s = 0;
    for (int i = begin; i < end; ++i) s += cnt[i];
    lds[tid] = s;
    __syncthreads();
    for (int off = 1; off < 1024; off <<= 1) {
        int v = (tid >= off) ? lds[tid - off] : 0;
        __syncthreads();
        lds[tid] += v;
        __syncthreads();
    }
    int run = (tid == 0) ? 0 : lds[tid - 1];
    for (int i = begin; i < end; ++i) {
        rowptr[i] = run;
        cursor[i] = run;
        run += cnt[i];
    }
    if (tid == 1023) rowptr[cN] = lds[1023];
}

// ---------------- scatter edges into CSR (by dst) ----------------
__global__ void scatter_kernel(const int* __restrict__ edge, int* __restrict__ cursor,
                               int* __restrict__ adj) {
    int e = blockIdx.x * blockDim.x + threadIdx.x;
    if (e < cE) {
        int d = edge[cE + e];
        int pos = atomicAdd(&cursor[d], 1);
        adj[pos] = edge[e];
    }
}

// ---------------- dinv = rsqrt(count_dst + 1) ----------------
__global__ void dinv_kernel(const int* __restrict__ count_dst, float* __restrict__ dinv) {
    int i = blockIdx.x * blockDim.x + threadIdx.x;
    if (i < cN) {
        dinv[i] = rsqrtf((float)(count_dst[i] + 1));
    }
}

// ---------------- x[:, 0:40] = logits ----------------
__global__ void copy_logits_kernel(const float* __restrict__ logits, float* __restrict__ x) {
    int idx = blockIdx.x * blockDim.x + threadIdx.x;
    if (idx < cN * cNUM_CLASSES) {
        int i = idx / cNUM_CLASSES;
        int c = idx - i * cNUM_CLASSES;
        x[(size_t)i * cIN_CH + c] = logits[idx];
    }
}

// ---------------- x[:, 104:136] = deg_table[clip(deg)] ----------------
__global__ void degemb_kernel(const int* __restrict__ count_src, const int* __restrict__ count_dst,
                              const float* __restrict__ deg_table, float* __restrict__ x) {
    int idx = blockIdx.x * blockDim.x + threadIdx.x;
    if (idx < cN * cDEG_HID) {
        int i = idx / cDEG_HID;
        int j = idx - i * cDEG_HID;
        int deg = count_src[i] + count_dst[i];
        if (deg > cMAX_DEG - 1) deg = cMAX_DEG - 1;
        x[(size_t)i * cIN_CH + cNUM_CLASSES + cFEAT_HID + j] = deg_table[deg * cDEG_HID + j];
    }
}

// ---------------- tiled register-blocked GEMM ----------------
// Block covers ROWS=32 rows x COLS cols. 4x4 micro-tile per thread.
// xs staged k-major (stride 36, conflict-free b128 over rows),
// ws staged native (stride COLS, conflict-free b128 over cols).
// K processed in chunks of KC to bound LDS.
template <int K, int KC, int OUTC, int COLS, int BLOCK, bool BIAS>
__global__ __launch_bounds__(BLOCK) void tile_gemm(const float* __restrict__ in,
                                                   const float* __restrict__ W,
                                                   const float* __restrict__ bias,
                                                   float* __restrict__ out,
                                                   int outstride, int outoffset) {
    constexpr int ROWS = 32;
    constexpr int RT = 8;            // row-tiles (4 rows each)
    constexpr int CT = COLS / 4;     // col-tiles
    static_assert(BLOCK == RT * CT, "block/tile mismatch");
    static_assert(K % KC == 0, "K must be divisible by KC");

    __shared__ float xs[KC][ROWS + 4];   // stride 36
    __shared__ float ws[KC][COLS];

    const int tid = threadIdx.x;
    const int rt = tid % RT;
    const int ct = tid / RT;
    const int rowbase = blockIdx.x * ROWS;
    const int r0 = rt * 4;
    const int c0 = ct * 4;

    float acc[4][4];
    #pragma unroll
    for (int i = 0; i < 4; ++i)
        #pragma unroll
        for (int j = 0; j < 4; ++j) acc[i][j] = 0.f;

    for (int kbase = 0; kbase < K; kbase += KC) {
        // stage W chunk (float4, zero-pad cols >= OUTC)
        for (int idx = tid; idx < KC * (COLS / 4); idx += BLOCK) {
            int k = idx / (COLS / 4);
            int cq = (idx % (COLS / 4)) * 4;
            float4 v = make_float4(0.f, 0.f, 0.f, 0.f);
            if (cq < OUTC) v = *(const float4*)&W[(size_t)(kbase + k) * OUTC + cq];
            *(float4*)&ws[k][cq] = v;
        }
        // stage x chunk transposed: xs[k][r] = in[(rowbase+r)*K + kbase+k]
        for (int idx = tid; idx < KC * ROWS; idx += BLOCK) {
            int r = idx / KC;
            int k = idx % KC;
            int rr = rowbase + r;
            if (rr > cN - 1) rr = cN - 1;
            xs[k][r] = in[(size_t)rr * K + kbase + k];
        }
        __syncthreads();

        #pragma unroll 4
        for (int k = 0; k < KC; ++k) {
            float4 xv = *(const float4*)&xs[k][r0];
            float4 wv = *(const float4*)&ws[k][c0];
            acc[0][0] += xv.x * wv.x; acc[0][1] += xv.x * wv.y; acc[0][2] += xv.x * wv.z; acc[0][3] += xv.x * wv.w;
            acc[1][0] += xv.y * wv.x; acc[1][1] += xv.y * wv.y; acc[1][2] += xv.y * wv.z; acc[1][3] += xv.y * wv.w;
            acc[2][0] += xv.z * wv.x; acc[2][1] += xv.z * wv.y; acc[2][2] += xv.z * wv.z; acc[2][3] += xv.z * wv.w;
            acc[3][0] += xv.w * wv.x; acc[3][1] += xv.w * wv.y; acc[3][2] += xv.w * wv.z; acc[3][3] += xv.w * wv.w;
        }
        __syncthreads();
    }

    if (c0 < OUTC) {
        float4 bv = make_float4(0.f, 0.f, 0.f, 0.f);
        if (BIAS) bv = *(const float4*)&bias[c0];
        #pragma unroll
        for (int i = 0; i < 4; ++i) {
            int r = rowbase + r0 + i;
            if (r < cN) {
                float4 v = make_float4(acc[i][0] + bv.x, acc[i][1] + bv.y,
                                       acc[i][2] + bv.z, acc[i][3] + bv.w);
                *(float4*)&out[(size_t)r * outstride + outoffset + c0] = v;
            }
        }
    }
}

// ---------------- GCN aggregate (vectorized): out[i,c] = di*sum_j dinv[j]*t[j,c] + di^2*t[i,c] + b[c]
template <int OUTC, int GROUP, bool RELU>
__global__ __launch_bounds__(256) void agg2_kernel(const float* __restrict__ t,
                                                   const int* __restrict__ rowptr,
                                                   const int* __restrict__ adj,
                                                   const float* __restrict__ dinv,
                                                   const float* __restrict__ b,
                                                   float* __restrict__ out) {
    constexpr int GPB = 256 / GROUP;  // row-groups per block
    const int tid = threadIdx.x;
    const int lane = tid % GROUP;
    const int row = blockIdx.x * GPB + tid / GROUP;
    const int c = lane * 4;
    if (row >= cN || c >= OUTC) return;

    const float di = dinv[row];
    const int beg = rowptr[row];
    const int end = rowptr[row + 1];

    float4 acc = make_float4(0.f, 0.f, 0.f, 0.f);
    for (int e = beg; e < end; ++e) {
        int j = adj[e];
        float vj = dinv[j];
        float4 tv = *(const float4*)&t[(size_t)j * OUTC + c];
        acc.x += vj * tv.x; acc.y += vj * tv.y; acc.z += vj * tv.z; acc.w += vj * tv.w;
    }
    float4 ts = *(const float4*)&t[(size_t)row * OUTC + c];
    float4 bv = *(const float4*)&b[c];
    float d2 = di * di;
    float4 r;
    r.x = di * acc.x + d2 * ts.x + bv.x;
    r.y = di * acc.y + d2 * ts.y + bv.y;
    r.z = di * acc.z + d2 * ts.z + bv.z;
    r.w = di * acc.w + d2 * ts.w + bv.w;
    if (RELU) {
        r.x = fmaxf(r.x, 0.f); r.y = fmaxf(r.y, 0.f);
        r.z = fmaxf(r.z, 0.f); r.w = fmaxf(r.w, 0.f);
    }
    *(float4*)&out[(size_t)row * OUTC + c] = r;
}

extern "C" void kernel_launch(void* const* d_in, const int* in_sizes, int n_in,
                              void* d_out, int out_size, void* d_ws, size_t ws_size,
                              hipStream_t stream) {
    const float* logits    = (const float*)d_in[0];
    const float* features  = (const float*)d_in[1];
    const int*   edge      = (const int*)d_in[2];
    const float* Wf        = (const float*)d_in[3];
    const float* bf        = (const float*)d_in[4];
    const float* deg_table = (const float*)d_in[5];
    const float* W1        = (const float*)d_in[6];
    const float* b1        = (const float*)d_in[7];
    const float* W2        = (const float*)d_in[8];
    const float* b2        = (const float*)d_in[9];
    const float* W3        = (const float*)d_in[10];
    const float* b3        = (const float*)d_in[11];
    float* out = (float*)d_out;

    // workspace carve-up
    int* count_src = (int*)d_ws;                 // N
    int* count_dst = count_src + cN;             // N
    int* rowptr    = count_dst + cN;             // N+1
    int* cursor    = rowptr + cN + 16;           // N (padded start)
    int* adj       = cursor + cN;                // E
    float* dinv    = (float*)(adj + cE);         // N
    float* x       = dinv + cN;                  // N*IN_CH
    float* t       = x + (size_t)cN * cIN_CH;    // N*HID
    float* h       = t + (size_t)cN * cHID;      // N*HID

    hipMemsetAsync(count_src, 0, 2 * cN * sizeof(int), stream);

    degree_kernel<<<(cE + 255) / 256, 256, 0, stream>>>(edge, count_src, count_dst);
    scan_kernel<<<1, 1024, 0, stream>>>(count_dst, rowptr, cursor);
    scatter_kernel<<<(cE + 255) / 256, 256, 0, stream>>>(edge, cursor, adj);
    dinv_kernel<<<(cN + 255) / 256, 256, 0, stream>>>(count_dst, dinv);

    copy_logits_kernel<<<(cN * cNUM_CLASSES + 255) / 256, 256, 0, stream>>>(logits, x);
    degemb_kernel<<<(cN * cDEG_HID + 255) / 256, 256, 0, stream>>>(count_src, count_dst, deg_table, x);

    constexpr int NBLK = (cN + 31) / 32; // 1563

    // featlin: x[:,40:104] = features @ Wf + bf    (K=256, OUTC=64)
    tile_gemm<cFEAT_DIM, 64, cFEAT_HID, 64, 128, true>
        <<<NBLK, 128, 0, stream>>>(features, Wf, bf, x, cIN_CH, cNUM_CLASSES);

    // conv1: t = x @ W1 ; h = relu(agg(t) + b1)
    tile_gemm<cIN_CH, 68, cHID, 128, 256, false>
        <<<NBLK, 256, 0, stream>>>(x, W1, nullptr, t, cHID, 0);
    agg2_kernel<cHID, 32, true><<<(cN + 7) / 8, 256, 0, stream>>>(t, rowptr, adj, dinv, b1, h);

    // conv2: t = h @ W2 ; h = relu(agg(t) + b2)
    tile_gemm<cHID, 64, cHID, 128, 256, false>
        <<<NBLK, 256, 0, stream>>>(h, W2, nullptr, t, cHID, 0);
    agg2_kernel<cHID, 32, true><<<(cN + 7) / 8, 256, 0, stream>>>(t, rowptr, adj, dinv, b2, h);

    // conv3: t = h @ W3 ; out = agg(t) + b3
    tile_gemm<cHID, 64, cNUM_CLASSES, 64, 128, false>
        <<<NBLK, 128, 0, stream>>>(h, W3, nullptr, t, cNUM_CLASSES, 0);
    agg2_kernel<cNUM_CLASSES, 16, false><<<(cN + 15) / 16, 256, 0, stream>>>(t, rowptr, adj, dinv, b3, out);
}

// Round 3
// 578.865 us; speedup vs baseline: 1.5889x; 1.1389x over previous
//
#include <hip/hip_runtime.h>
#include <hip/hip_bf16.h>

// Problem constants (match reference)
constexpr int cN = 50000;
constexpr int cE = 800000;
constexpr int cNUM_CLASSES = 40;
constexpr int cFEAT_DIM = 256;
constexpr int cFEAT_HID = 64;
constexpr int cDEG_HID = 32;
constexpr int cHID = 128;
constexpr int cIN_CH = cNUM_CLASSES + cFEAT_HID + cDEG_HID; // 136
constexpr int cMAX_DEG = 256;
constexpr int cSCAN_NB = (cN + 255) / 256; // 196

// ---------------- degree histograms ----------------
__global__ void degree_kernel(const int* __restrict__ edge,
                              int* __restrict__ count_src, int* __restrict__ count_dst) {
    int e = blockIdx.x * blockDim.x + threadIdx.x;
    if (e < cE) {
        atomicAdd(&count_src[edge[e]], 1);
        atomicAdd(&count_dst[edge[cE + e]], 1);
    }
}

// ---------------- hierarchical scan, phase 1: per-block sums ----------------
__global__ __launch_bounds__(256) void block_sum_kernel(const int* __restrict__ cnt,
                                                        int* __restrict__ bsum) {
    __shared__ int s[256];
    int tid = threadIdx.x;
    int i = blockIdx.x * 256 + tid;
    int v = (i < cN) ? cnt[i] : 0;
    s[tid] = v;
    __syncthreads();
    #pragma unroll
    for (int off = 128; off > 0; off >>= 1) {
        if (tid < off) s[tid] += s[tid + off];
        __syncthreads();
    }
    if (tid == 0) bsum[blockIdx.x] = s[0];
}

// ---------------- phase 2: exclusive scan of block sums (single small block) ----------------
__global__ __launch_bounds__(256) void scan_sums_kernel(const int* __restrict__ bsum,
                                                        int* __restrict__ boff) {
    __shared__ int s[256];
    int tid = threadIdx.x;
    int v = (tid < cSCAN_NB) ? bsum[tid] : 0;
    s[tid] = v;
    __syncthreads();
    #pragma unroll
    for (int off = 1; off < 256; off <<= 1) {
        int t = (tid >= off) ? s[tid - off] : 0;
        __syncthreads();
        s[tid] += t;
        __syncthreads();
    }
    if (tid < cSCAN_NB) boff[tid] = s[tid] - v; // exclusive
}

// ---------------- phase 3: in-block scan + writeback (rowptr, cursor, dinv) ----------------
__global__ __launch_bounds__(256) void write_rowptr_kernel(const int* __restrict__ cnt,
                                                           const int* __restrict__ boff,
                                                           int* __restrict__ rowptr,
                                                           int* __restrict__ cursor,
                                                           float* __restrict__ dinv) {
    __shared__ int s[256];
    int tid = threadIdx.x;
    int i = blockIdx.x * 256 + tid;
    int v = (i < cN) ? cnt[i] : 0;
    s[tid] = v;
    __syncthreads();
    #pragma unroll
    for (int off = 1; off < 256; off <<= 1) {
        int t = (tid >= off) ? s[tid - off] : 0;
        __syncthreads();
        s[tid] += t;
        __syncthreads();
    }
    if (i < cN) {
        int ex = boff[blockIdx.x] + s[tid] - v;
        rowptr[i] = ex;
        cursor[i] = ex;
        dinv[i] = rsqrtf((float)(v + 1));
    }
    if (i == 0) rowptr[cN] = cE; // total dst-degree == E by construction
}

// ---------------- scatter edges into CSR (by dst) ----------------
__global__ void scatter_kernel(const int* __restrict__ edge, int* __restrict__ cursor,
                               int* __restrict__ adj) {
    int e = blockIdx.x * blockDim.x + threadIdx.x;
    if (e < cE) {
        int d = edge[cE + e];
        int pos = atomicAdd(&cursor[d], 1);
        adj[pos] = edge[e];
    }
}

// ---------------- x[:, 0:40] = logits ----------------
__global__ void copy_logits_kernel(const float* __restrict__ logits, float* __restrict__ x) {
    int idx = blockIdx.x * blockDim.x + threadIdx.x;
    if (idx < cN * cNUM_CLASSES) {
        int i = idx / cNUM_CLASSES;
        int c = idx - i * cNUM_CLASSES;
        x[(size_t)i * cIN_CH + c] = logits[idx];
    }
}

// ---------------- x[:, 104:136] = deg_table[clip(deg)] ----------------
__global__ void degemb_kernel(const int* __restrict__ count_src, const int* __restrict__ count_dst,
                              const float* __restrict__ deg_table, float* __restrict__ x) {
    int idx = blockIdx.x * blockDim.x + threadIdx.x;
    if (idx < cN * cDEG_HID) {
        int i = idx / cDEG_HID;
        int j = idx - i * cDEG_HID;
        int deg = count_src[i] + count_dst[i];
        if (deg > cMAX_DEG - 1) deg = cMAX_DEG - 1;
        x[(size_t)i * cIN_CH + cNUM_CLASSES + cFEAT_HID + j] = deg_table[deg * cDEG_HID + j];
    }
}

// ---------------- tiled register-blocked GEMM ----------------
template <int K, int KC, int OUTC, int COLS, int BLOCK, bool BIAS>
__global__ __launch_bounds__(BLOCK) void tile_gemm(const float* __restrict__ in,
                                                   const float* __restrict__ W,
                                                   const float* __restrict__ bias,
                                                   float* __restrict__ out,
                                                   int outstride, int outoffset) {
    constexpr int ROWS = 32;
    constexpr int RT = 8;            // row-tiles (4 rows each)
    constexpr int CT = COLS / 4;     // col-tiles
    static_assert(BLOCK == RT * CT, "block/tile mismatch");
    static_assert(K % KC == 0, "K must be divisible by KC");

    __shared__ float xs[KC][ROWS + 4];   // stride 36
    __shared__ float ws[KC][COLS];

    const int tid = threadIdx.x;
    const int rt = tid % RT;
    const int ct = tid / RT;
    const int rowbase = blockIdx.x * ROWS;
    const int r0 = rt * 4;
    const int c0 = ct * 4;

    float acc[4][4];
    #pragma unroll
    for (int i = 0; i < 4; ++i)
        #pragma unroll
        for (int j = 0; j < 4; ++j) acc[i][j] = 0.f;

    for (int kbase = 0; kbase < K; kbase += KC) {
        for (int idx = tid; idx < KC * (COLS / 4); idx += BLOCK) {
            int k = idx / (COLS / 4);
            int cq = (idx % (COLS / 4)) * 4;
            float4 v = make_float4(0.f, 0.f, 0.f, 0.f);
            if (cq < OUTC) v = *(const float4*)&W[(size_t)(kbase + k) * OUTC + cq];
            *(float4*)&ws[k][cq] = v;
        }
        for (int idx = tid; idx < KC * ROWS; idx += BLOCK) {
            int r = idx / KC;
            int k = idx % KC;
            int rr = rowbase + r;
            if (rr > cN - 1) rr = cN - 1;
            xs[k][r] = in[(size_t)rr * K + kbase + k];
        }
        __syncthreads();

        #pragma unroll 4
        for (int k = 0; k < KC; ++k) {
            float4 xv = *(const float4*)&xs[k][r0];
            float4 wv = *(const float4*)&ws[k][c0];
            acc[0][0] += xv.x * wv.x; acc[0][1] += xv.x * wv.y; acc[0][2] += xv.x * wv.z; acc[0][3] += xv.x * wv.w;
            acc[1][0] += xv.y * wv.x; acc[1][1] += xv.y * wv.y; acc[1][2] += xv.y * wv.z; acc[1][3] += xv.y * wv.w;
            acc[2][0] += xv.z * wv.x; acc[2][1] += xv.z * wv.y; acc[2][2] += xv.z * wv.z; acc[2][3] += xv.z * wv.w;
            acc[3][0] += xv.w * wv.x; acc[3][1] += xv.w * wv.y; acc[3][2] += xv.w * wv.z; acc[3][3] += xv.w * wv.w;
        }
        __syncthreads();
    }

    if (c0 < OUTC) {
        float4 bv = make_float4(0.f, 0.f, 0.f, 0.f);
        if (BIAS) bv = *(const float4*)&bias[c0];
        #pragma unroll
        for (int i = 0; i < 4; ++i) {
            int r = rowbase + r0 + i;
            if (r < cN) {
                float4 v = make_float4(acc[i][0] + bv.x, acc[i][1] + bv.y,
                                       acc[i][2] + bv.z, acc[i][3] + bv.w);
                *(float4*)&out[(size_t)r * outstride + outoffset + c0] = v;
            }
        }
    }
}

// ---------------- GCN aggregate (vectorized) ----------------
template <int OUTC, int GROUP, bool RELU>
__global__ __launch_bounds__(256) void agg2_kernel(const float* __restrict__ t,
                                                   const int* __restrict__ rowptr,
                                                   const int* __restrict__ adj,
                                                   const float* __restrict__ dinv,
                                                   const float* __restrict__ b,
                                                   float* __restrict__ out) {
    constexpr int GPB = 256 / GROUP;  // row-groups per block
    const int tid = threadIdx.x;
    const int lane = tid % GROUP;
    const int row = blockIdx.x * GPB + tid / GROUP;
    const int c = lane * 4;
    if (row >= cN || c >= OUTC) return;

    const float di = dinv[row];
    const int beg = rowptr[row];
    const int end = rowptr[row + 1];

    float4 acc = make_float4(0.f, 0.f, 0.f, 0.f);
    for (int e = beg; e < end; ++e) {
        int j = adj[e];
        float vj = dinv[j];
        float4 tv = *(const float4*)&t[(size_t)j * OUTC + c];
        acc.x += vj * tv.x; acc.y += vj * tv.y; acc.z += vj * tv.z; acc.w += vj * tv.w;
    }
    float4 ts = *(const float4*)&t[(size_t)row * OUTC + c];
    float4 bv = *(const float4*)&b[c];
    float d2 = di * di;
    float4 r;
    r.x = di * acc.x + d2 * ts.x + bv.x;
    r.y = di * acc.y + d2 * ts.y + bv.y;
    r.z = di * acc.z + d2 * ts.z + bv.z;
    r.w = di * acc.w + d2 * ts.w + bv.w;
    if (RELU) {
        r.x = fmaxf(r.x, 0.f); r.y = fmaxf(r.y, 0.f);
        r.z = fmaxf(r.z, 0.f); r.w = fmaxf(r.w, 0.f);
    }
    *(float4*)&out[(size_t)row * OUTC + c] = r;
}

extern "C" void kernel_launch(void* const* d_in, const int* in_sizes, int n_in,
                              void* d_out, int out_size, void* d_ws, size_t ws_size,
                              hipStream_t stream) {
    const float* logits    = (const float*)d_in[0];
    const float* features  = (const float*)d_in[1];
    const int*   edge      = (const int*)d_in[2];
    const float* Wf        = (const float*)d_in[3];
    const float* bf        = (const float*)d_in[4];
    const float* deg_table = (const float*)d_in[5];
    const float* W1        = (const float*)d_in[6];
    const float* b1        = (const float*)d_in[7];
    const float* W2        = (const float*)d_in[8];
    const float* b2        = (const float*)d_in[9];
    const float* W3        = (const float*)d_in[10];
    const float* b3        = (const float*)d_in[11];
    float* out = (float*)d_out;

    // workspace carve-up
    int* count_src = (int*)d_ws;                 // N
    int* count_dst = count_src + cN;             // N
    int* rowptr    = count_dst + cN;             // N+1
    int* cursor    = rowptr + cN + 16;           // N (padded start)
    int* adj       = cursor + cN;                // E
    int* bsum      = adj + cE;                   // SCAN_NB
    int* boff      = bsum + cSCAN_NB + 4;        // SCAN_NB
    float* dinv    = (float*)(boff + cSCAN_NB + 4); // N
    float* x       = dinv + cN;                  // N*IN_CH
    float* t       = x + (size_t)cN * cIN_CH;    // N*HID
    float* h       = t + (size_t)cN * cHID;      // N*HID

    hipMemsetAsync(count_src, 0, 2 * cN * sizeof(int), stream);

    degree_kernel<<<(cE + 255) / 256, 256, 0, stream>>>(edge, count_src, count_dst);
    block_sum_kernel<<<cSCAN_NB, 256, 0, stream>>>(count_dst, bsum);
    scan_sums_kernel<<<1, 256, 0, stream>>>(bsum, boff);
    write_rowptr_kernel<<<cSCAN_NB, 256, 0, stream>>>(count_dst, boff, rowptr, cursor, dinv);
    scatter_kernel<<<(cE + 255) / 256, 256, 0, stream>>>(edge, cursor, adj);

    copy_logits_kernel<<<(cN * cNUM_CLASSES + 255) / 256, 256, 0, stream>>>(logits, x);
    degemb_kernel<<<(cN * cDEG_HID + 255) / 256, 256, 0, stream>>>(count_src, count_dst, deg_table, x);

    constexpr int NBLK = (cN + 31) / 32; // 1563

    // featlin: x[:,40:104] = features @ Wf + bf    (K=256, OUTC=64)
    tile_gemm<cFEAT_DIM, 64, cFEAT_HID, 64, 128, true>
        <<<NBLK, 128, 0, stream>>>(features, Wf, bf, x, cIN_CH, cNUM_CLASSES);

    // conv1: t = x @ W1 ; h = relu(agg(t) + b1)
    tile_gemm<cIN_CH, 68, cHID, 128, 256, false>
        <<<NBLK, 256, 0, stream>>>(x, W1, nullptr, t, cHID, 0);
    agg2_kernel<cHID, 32, true><<<(cN + 7) / 8, 256, 0, stream>>>(t, rowptr, adj, dinv, b1, h);

    // conv2: t = h @ W2 ; h = relu(agg(t) + b2)
    tile_gemm<cHID, 64, cHID, 128, 256, false>
        <<<NBLK, 256, 0, stream>>>(h, W2, nullptr, t, cHID, 0);
    agg2_kernel<cHID, 32, true><<<(cN + 7) / 8, 256, 0, stream>>>(t, rowptr, adj, dinv, b2, h);

    // conv3: t = h @ W3 ; out = agg(t) + b3
    tile_gemm<cHID, 64, cNUM_CLASSES, 64, 128, false>
        <<<NBLK, 128, 0, stream>>>(h, W3, nullptr, t, cNUM_CLASSES, 0);
    agg2_kernel<cNUM_CLASSES, 16, false><<<(cN + 15) / 16, 256, 0, stream>>>(t, rowptr, adj, dinv, b3, out);
}

// Round 4
// 486.060 us; speedup vs baseline: 1.8922x; 1.1909x over previous
//
#include <hip/hip_runtime.h>
#include <hip/hip_bf16.h>

// Problem constants (match reference)
constexpr int cN = 50000;
constexpr int cE = 800000;
constexpr int cNUM_CLASSES = 40;
constexpr int cFEAT_DIM = 256;
constexpr int cFEAT_HID = 64;
constexpr int cDEG_HID = 32;
constexpr int cHID = 128;
constexpr int cIN_CH = cNUM_CLASSES + cFEAT_HID + cDEG_HID; // 136
constexpr int cMAX_DEG = 256;
constexpr int cSCAN_NB = (cN + 255) / 256; // 196

typedef unsigned short ushort8_t __attribute__((ext_vector_type(8)));
typedef unsigned short ushort4_t __attribute__((ext_vector_type(4)));

__device__ __forceinline__ unsigned short f2bf(float f) {
    unsigned u = __builtin_bit_cast(unsigned, f);
    u += 0x7fff + ((u >> 16) & 1); // RNE
    return (unsigned short)(u >> 16);
}
__device__ __forceinline__ float bf2f(unsigned short s) {
    unsigned u = ((unsigned)s) << 16;
    return __builtin_bit_cast(float, u);
}

// ---------------- degree histograms ----------------
__global__ void degree_kernel(const int* __restrict__ edge,
                              int* __restrict__ count_src, int* __restrict__ count_dst) {
    int e = blockIdx.x * blockDim.x + threadIdx.x;
    if (e < cE) {
        atomicAdd(&count_src[edge[e]], 1);
        atomicAdd(&count_dst[edge[cE + e]], 1);
    }
}

// ---------------- hierarchical scan, phase 1: per-block sums ----------------
__global__ __launch_bounds__(256) void block_sum_kernel(const int* __restrict__ cnt,
                                                        int* __restrict__ bsum) {
    __shared__ int s[256];
    int tid = threadIdx.x;
    int i = blockIdx.x * 256 + tid;
    int v = (i < cN) ? cnt[i] : 0;
    s[tid] = v;
    __syncthreads();
    #pragma unroll
    for (int off = 128; off > 0; off >>= 1) {
        if (tid < off) s[tid] += s[tid + off];
        __syncthreads();
    }
    if (tid == 0) bsum[blockIdx.x] = s[0];
}

// ---------------- phase 2: exclusive scan of block sums ----------------
__global__ __launch_bounds__(256) void scan_sums_kernel(const int* __restrict__ bsum,
                                                        int* __restrict__ boff) {
    __shared__ int s[256];
    int tid = threadIdx.x;
    int v = (tid < cSCAN_NB) ? bsum[tid] : 0;
    s[tid] = v;
    __syncthreads();
    #pragma unroll
    for (int off = 1; off < 256; off <<= 1) {
        int t = (tid >= off) ? s[tid - off] : 0;
        __syncthreads();
        s[tid] += t;
        __syncthreads();
    }
    if (tid < cSCAN_NB) boff[tid] = s[tid] - v; // exclusive
}

// ---------------- phase 3: in-block scan + writeback (rowptr, cursor, dinv) ----------------
__global__ __launch_bounds__(256) void write_rowptr_kernel(const int* __restrict__ cnt,
                                                           const int* __restrict__ boff,
                                                           int* __restrict__ rowptr,
                                                           int* __restrict__ cursor,
                                                           float* __restrict__ dinv) {
    __shared__ int s[256];
    int tid = threadIdx.x;
    int i = blockIdx.x * 256 + tid;
    int v = (i < cN) ? cnt[i] : 0;
    s[tid] = v;
    __syncthreads();
    #pragma unroll
    for (int off = 1; off < 256; off <<= 1) {
        int t = (tid >= off) ? s[tid - off] : 0;
        __syncthreads();
        s[tid] += t;
        __syncthreads();
    }
    if (i < cN) {
        int ex = boff[blockIdx.x] + s[tid] - v;
        rowptr[i] = ex;
        cursor[i] = ex;
        dinv[i] = rsqrtf((float)(v + 1));
    }
    if (i == 0) rowptr[cN] = cE;
}

// ---------------- scatter edges into CSR (by dst) ----------------
__global__ void scatter_kernel(const int* __restrict__ edge, int* __restrict__ cursor,
                               int* __restrict__ adj) {
    int e = blockIdx.x * blockDim.x + threadIdx.x;
    if (e < cE) {
        int d = edge[cE + e];
        int pos = atomicAdd(&cursor[d], 1);
        adj[pos] = edge[e];
    }
}

// ---------------- x[:, 0:40] = logits ----------------
__global__ void copy_logits_kernel(const float* __restrict__ logits, float* __restrict__ x) {
    int idx = blockIdx.x * blockDim.x + threadIdx.x;
    if (idx < cN * cNUM_CLASSES) {
        int i = idx / cNUM_CLASSES;
        int c = idx - i * cNUM_CLASSES;
        x[(size_t)i * cIN_CH + c] = logits[idx];
    }
}

// ---------------- x[:, 104:136] = deg_table[clip(deg)] ----------------
__global__ void degemb_kernel(const int* __restrict__ count_src, const int* __restrict__ count_dst,
                              const float* __restrict__ deg_table, float* __restrict__ x) {
    int idx = blockIdx.x * blockDim.x + threadIdx.x;
    if (idx < cN * cDEG_HID) {
        int i = idx / cDEG_HID;
        int j = idx - i * cDEG_HID;
        int deg = count_src[i] + count_dst[i];
        if (deg > cMAX_DEG - 1) deg = cMAX_DEG - 1;
        x[(size_t)i * cIN_CH + cNUM_CLASSES + cFEAT_HID + j] = deg_table[deg * cDEG_HID + j];
    }
}

// ---------------- tiled register-blocked GEMM (fp32 math, fp32 or bf16 output) ----------------
template <int K, int KC, int OUTC, int COLS, int BLOCK, bool BIAS, typename OutT>
__global__ __launch_bounds__(BLOCK) void tile_gemm(const float* __restrict__ in,
                                                   const float* __restrict__ W,
                                                   const float* __restrict__ bias,
                                                   OutT* __restrict__ out,
                                                   int outstride, int outoffset) {
    constexpr int ROWS = 32;
    constexpr int RT = 8;            // row-tiles (4 rows each)
    constexpr int CT = COLS / 4;     // col-tiles
    static_assert(BLOCK == RT * CT, "block/tile mismatch");
    static_assert(K % KC == 0, "K must be divisible by KC");

    __shared__ float xs[KC][ROWS + 4];   // stride 36
    __shared__ float ws[KC][COLS];

    const int tid = threadIdx.x;
    const int rt = tid % RT;
    const int ct = tid / RT;
    const int rowbase = blockIdx.x * ROWS;
    const int r0 = rt * 4;
    const int c0 = ct * 4;

    float acc[4][4];
    #pragma unroll
    for (int i = 0; i < 4; ++i)
        #pragma unroll
        for (int j = 0; j < 4; ++j) acc[i][j] = 0.f;

    for (int kbase = 0; kbase < K; kbase += KC) {
        for (int idx = tid; idx < KC * (COLS / 4); idx += BLOCK) {
            int k = idx / (COLS / 4);
            int cq = (idx % (COLS / 4)) * 4;
            float4 v = make_float4(0.f, 0.f, 0.f, 0.f);
            if (cq < OUTC) v = *(const float4*)&W[(size_t)(kbase + k) * OUTC + cq];
            *(float4*)&ws[k][cq] = v;
        }
        for (int idx = tid; idx < KC * ROWS; idx += BLOCK) {
            int r = idx / KC;
            int k = idx % KC;
            int rr = rowbase + r;
            if (rr > cN - 1) rr = cN - 1;
            xs[k][r] = in[(size_t)rr * K + kbase + k];
        }
        __syncthreads();

        #pragma unroll 4
        for (int k = 0; k < KC; ++k) {
            float4 xv = *(const float4*)&xs[k][r0];
            float4 wv = *(const float4*)&ws[k][c0];
            acc[0][0] += xv.x * wv.x; acc[0][1] += xv.x * wv.y; acc[0][2] += xv.x * wv.z; acc[0][3] += xv.x * wv.w;
            acc[1][0] += xv.y * wv.x; acc[1][1] += xv.y * wv.y; acc[1][2] += xv.y * wv.z; acc[1][3] += xv.y * wv.w;
            acc[2][0] += xv.z * wv.x; acc[2][1] += xv.z * wv.y; acc[2][2] += xv.z * wv.z; acc[2][3] += xv.z * wv.w;
            acc[3][0] += xv.w * wv.x; acc[3][1] += xv.w * wv.y; acc[3][2] += xv.w * wv.z; acc[3][3] += xv.w * wv.w;
        }
        __syncthreads();
    }

    if (c0 < OUTC) {
        float4 bv = make_float4(0.f, 0.f, 0.f, 0.f);
        if (BIAS) bv = *(const float4*)&bias[c0];
        #pragma unroll
        for (int i = 0; i < 4; ++i) {
            int r = rowbase + r0 + i;
            if (r < cN) {
                float4 v = make_float4(acc[i][0] + bv.x, acc[i][1] + bv.y,
                                       acc[i][2] + bv.z, acc[i][3] + bv.w);
                if constexpr (sizeof(OutT) == 2) {
                    ushort4_t p = { f2bf(v.x), f2bf(v.y), f2bf(v.z), f2bf(v.w) };
                    *(ushort4_t*)&out[(size_t)r * outstride + outoffset + c0] = p;
                } else {
                    *(float4*)&out[(size_t)r * outstride + outoffset + c0] = v;
                }
            }
        }
    }
}

// ---------------- GCN aggregate over bf16 t, 128 channels ----------------
template <bool RELU>
__global__ __launch_bounds__(256) void agg_bf128(const unsigned short* __restrict__ t,
                                                 const int* __restrict__ rowptr,
                                                 const int* __restrict__ adj,
                                                 const float* __restrict__ dinv,
                                                 const float* __restrict__ b,
                                                 float* __restrict__ out) {
    const int tid = threadIdx.x;
    const int lane = tid & 15;
    const int row = blockIdx.x * 16 + (tid >> 4);
    if (row >= cN) return;
    const int c = lane * 8;
    const float di = dinv[row];
    const int beg = rowptr[row], end = rowptr[row + 1];
    float acc[8];
    #pragma unroll
    for (int k = 0; k < 8; ++k) acc[k] = 0.f;
    for (int e = beg; e < end; ++e) {
        int j = adj[e];
        float vj = dinv[j];
        ushort8_t tv = *(const ushort8_t*)&t[(size_t)j * cHID + c];
        #pragma unroll
        for (int k = 0; k < 8; ++k) acc[k] += vj * bf2f(tv[k]);
    }
    ushort8_t ts = *(const ushort8_t*)&t[(size_t)row * cHID + c];
    const float d2 = di * di;
    float r[8];
    #pragma unroll
    for (int k = 0; k < 8; ++k) {
        r[k] = di * acc[k] + d2 * bf2f(ts[k]) + b[c + k];
        if (RELU) r[k] = fmaxf(r[k], 0.f);
    }
    float4 v0 = make_float4(r[0], r[1], r[2], r[3]);
    float4 v1 = make_float4(r[4], r[5], r[6], r[7]);
    *(float4*)&out[(size_t)row * cHID + c] = v0;
    *(float4*)&out[(size_t)row * cHID + c + 4] = v1;
}

// ---------------- GCN aggregate over bf16 t, 40 channels (final, no relu) ----------------
__global__ __launch_bounds__(256) void agg_bf40(const unsigned short* __restrict__ t,
                                                const int* __restrict__ rowptr,
                                                const int* __restrict__ adj,
                                                const float* __restrict__ dinv,
                                                const float* __restrict__ b,
                                                float* __restrict__ out) {
    const int tid = threadIdx.x;
    const int lane = tid & 7;
    const int row = blockIdx.x * 32 + (tid >> 3);
    if (row >= cN) return;
    const int c = lane * 8;
    if (c >= cNUM_CLASSES) return;   // lanes 5-7 idle
    const float di = dinv[row];
    const int beg = rowptr[row], end = rowptr[row + 1];
    float acc[8];
    #pragma unroll
    for (int k = 0; k < 8; ++k) acc[k] = 0.f;
    for (int e = beg; e < end; ++e) {
        int j = adj[e];
        float vj = dinv[j];
        ushort8_t tv = *(const ushort8_t*)&t[(size_t)j * cNUM_CLASSES + c];
        #pragma unroll
        for (int k = 0; k < 8; ++k) acc[k] += vj * bf2f(tv[k]);
    }
    ushort8_t ts = *(const ushort8_t*)&t[(size_t)row * cNUM_CLASSES + c];
    const float d2 = di * di;
    float r[8];
    #pragma unroll
    for (int k = 0; k < 8; ++k) r[k] = di * acc[k] + d2 * bf2f(ts[k]) + b[c + k];
    float4 v0 = make_float4(r[0], r[1], r[2], r[3]);
    float4 v1 = make_float4(r[4], r[5], r[6], r[7]);
    *(float4*)&out[(size_t)row * cNUM_CLASSES + c] = v0;
    *(float4*)&out[(size_t)row * cNUM_CLASSES + c + 4] = v1;
}

extern "C" void kernel_launch(void* const* d_in, const int* in_sizes, int n_in,
                              void* d_out, int out_size, void* d_ws, size_t ws_size,
                              hipStream_t stream) {
    const float* logits    = (const float*)d_in[0];
    const float* features  = (const float*)d_in[1];
    const int*   edge      = (const int*)d_in[2];
    const float* Wf        = (const float*)d_in[3];
    const float* bf        = (const float*)d_in[4];
    const float* deg_table = (const float*)d_in[5];
    const float* W1        = (const float*)d_in[6];
    const float* b1        = (const float*)d_in[7];
    const float* W2        = (const float*)d_in[8];
    const float* b2        = (const float*)d_in[9];
    const float* W3        = (const float*)d_in[10];
    const float* b3        = (const float*)d_in[11];
    float* out = (float*)d_out;

    // workspace carve-up (all offsets keep 16B alignment)
    int* count_src = (int*)d_ws;                 // N
    int* count_dst = count_src + cN;             // N
    int* rowptr    = count_dst + cN;             // N+1 (pad to +16)
    int* cursor    = rowptr + cN + 16;           // N
    int* adj       = cursor + cN;                // E
    int* bsum      = adj + cE;                   // 256
    int* boff      = bsum + 256;                 // 256
    float* dinv    = (float*)(boff + 256);       // N
    float* x       = dinv + cN;                  // N*IN_CH
    float* h       = x + (size_t)cN * cIN_CH;    // N*HID fp32
    unsigned short* tb = (unsigned short*)(h + (size_t)cN * cHID); // N*HID bf16

    hipMemsetAsync(count_src, 0, 2 * cN * sizeof(int), stream);

    degree_kernel<<<(cE + 255) / 256, 256, 0, stream>>>(edge, count_src, count_dst);
    block_sum_kernel<<<cSCAN_NB, 256, 0, stream>>>(count_dst, bsum);
    scan_sums_kernel<<<1, 256, 0, stream>>>(bsum, boff);
    write_rowptr_kernel<<<cSCAN_NB, 256, 0, stream>>>(count_dst, boff, rowptr, cursor, dinv);
    scatter_kernel<<<(cE + 255) / 256, 256, 0, stream>>>(edge, cursor, adj);

    copy_logits_kernel<<<(cN * cNUM_CLASSES + 255) / 256, 256, 0, stream>>>(logits, x);
    degemb_kernel<<<(cN * cDEG_HID + 255) / 256, 256, 0, stream>>>(count_src, count_dst, deg_table, x);

    constexpr int NBLK = (cN + 31) / 32; // 1563

    // featlin: x[:,40:104] = features @ Wf + bf
    tile_gemm<cFEAT_DIM, 64, cFEAT_HID, 64, 128, true, float>
        <<<NBLK, 128, 0, stream>>>(features, Wf, bf, x, cIN_CH, cNUM_CLASSES);

    // conv1: tb = bf16(x @ W1) ; h = relu(agg(tb) + b1)
    tile_gemm<cIN_CH, 68, cHID, 128, 256, false, unsigned short>
        <<<NBLK, 256, 0, stream>>>(x, W1, nullptr, tb, cHID, 0);
    agg_bf128<true><<<(cN + 15) / 16, 256, 0, stream>>>(tb, rowptr, adj, dinv, b1, h);

    // conv2: tb = bf16(h @ W2) ; h = relu(agg(tb) + b2)
    tile_gemm<cHID, 64, cHID, 128, 256, false, unsigned short>
        <<<NBLK, 256, 0, stream>>>(h, W2, nullptr, tb, cHID, 0);
    agg_bf128<true><<<(cN + 15) / 16, 256, 0, stream>>>(tb, rowptr, adj, dinv, b2, h);

    // conv3: tb = bf16(h @ W3) ; out = agg(tb) + b3
    tile_gemm<cHID, 64, cNUM_CLASSES, 64, 128, false, unsigned short>
        <<<NBLK, 128, 0, stream>>>(h, W3, nullptr, tb, cNUM_CLASSES, 0);
    agg_bf40<<<(cN + 31) / 32, 256, 0, stream>>>(tb, rowptr, adj, dinv, b3, out);
}